// Round 1
// baseline (110.933 us; speedup 1.0000x reference)
//
#include <hip/hip_runtime.h>
#include <math.h>

#define LNUM 6
#define BNUM 8
#define NNUM 300
#define CNUM 20
#define HW   784
#define GH   448
#define NW   13   // mask words (784 bits -> 13 x u64)
#define AW   5    // adjacency row words (300 bits -> 5 x u64)
#define TILES 56
#define TR    8   // rows per bce tile (56*8 = 448)

// ---- device scratch (recomputed every launch; no cross-launch state except g_acc, re-zeroed) ----
__device__ float              g_rm [BNUM*NNUM*HW];
__device__ unsigned long long g_T  [BNUM*NNUM*NW];
__device__ int                g_s  [BNUM*NNUM];
__device__ unsigned long long g_adj[BNUM*NNUM*AW];
__device__ unsigned long long g_fin[BNUM*CNUM*AW];
__device__ int                g_cnt[BNUM*CNUM];
__device__ float              g_mm [BNUM*CNUM*HW];
__device__ double             g_acc;

__global__ void k_zero() { g_acc = 0.0; }

// One block per (b,n): mean over L, relu, max-normalize, write rm + bitmask + popcount.
__global__ void k_rm(const float* __restrict__ sm) {
    int bn  = blockIdx.x;
    int tid = threadIdx.x;               // 256
    __shared__ float wmax[4];
    __shared__ int   scount;
    if (tid == 0) scount = 0;
    const size_t lstride = (size_t)BNUM * NNUM * HW;
    const float* base = sm + (size_t)bn * HW;
    float v[4];
    float lm = 0.0f;
    #pragma unroll
    for (int k = 0; k < 4; ++k) {
        int p = k * 256 + tid;
        float a = 0.0f;
        if (p < HW) {
            #pragma unroll
            for (int l = 0; l < LNUM; ++l) a += base[(size_t)l * lstride + p];
            a = __fdiv_rn(a, 6.0f);      // jnp.mean: sum / L in f32
            a = fmaxf(a, 0.0f);          // relu
        }
        v[k] = a;
        lm = fmaxf(lm, a);
    }
    #pragma unroll
    for (int off = 32; off; off >>= 1) lm = fmaxf(lm, __shfl_xor(lm, off));
    if ((tid & 63) == 0) wmax[tid >> 6] = lm;
    __syncthreads();
    float mx = fmaxf(fmaxf(wmax[0], wmax[1]), fmaxf(wmax[2], wmax[3]));
    float d = mx + 1e-6f;
    #pragma unroll
    for (int k = 0; k < 4; ++k) {
        int p = k * 256 + tid;
        float nv = __fdiv_rn(v[k], d);   // IEEE divide, matches reference rounding
        if (p < HW) g_rm[(size_t)bn * HW + p] = nv;
        bool pr = (p < HW) && (nv > 0.7f);
        unsigned long long ball = __ballot(pr);
        int word = k * 4 + (tid >> 6);
        if ((tid & 63) == 0 && word < NW) {
            g_T[(size_t)bn * NW + word] = ball;
            atomicAdd(&scount, __popcll(ball));
        }
    }
    __syncthreads();
    if (tid == 0) g_s[bn] = scount;
}

// One block per (b,i): adjacency row i via popcount(AND) + exact f32 replication of (iou+dice)/2 > 0.5
__global__ void k_adj() {
    int blk = blockIdx.x;                // b*300 + i
    int b = blk / NNUM;
    int tid = threadIdx.x;               // 320 (5 waves)
    __shared__ unsigned long long Ti[NW];
    __shared__ int si_sh;
    if (tid < NW)  Ti[tid] = g_T[(size_t)blk * NW + tid];
    if (tid == NW) si_sh = g_s[blk];
    __syncthreads();
    bool a = false;
    int j = tid;
    if (j < NNUM) {
        const unsigned long long* Tj = &g_T[((size_t)b * NNUM + j) * NW];
        int inter = 0;
        #pragma unroll
        for (int w = 0; w < NW; ++w) inter += __popcll(Ti[w] & Tj[w]);
        int si = si_sh, sj = g_s[b * NNUM + j];
        int uni = si + sj - inter, tot = si + sj;
        float iou  = (uni == 0) ? 1.0f : __fdiv_rn((float)inter, (float)uni);
        float dice = (tot == 0) ? 1.0f : __fdiv_rn(2.0f * (float)inter, (float)tot);
        a = (0.5f * (iou + dice)) > 0.5f;
    }
    unsigned long long ball = __ballot(a);
    if ((tid & 63) == 0) g_adj[(size_t)blk * AW + (tid >> 6)] = ball;
}

// One wave per (b,c): greedy transitive expansion to fixed point on the bitset graph.
__global__ void k_cluster(const float* __restrict__ score, const int* __restrict__ label) {
    int blk = blockIdx.x;                // b*C + c
    if (label[blk] == 0) return;         // inactive -> never consumed downstream
    int b = blk / CNUM, c = blk - b * CNUM;
    int lane = threadIdx.x;              // 64
    __shared__ unsigned long long adj_sh[NNUM][AW];
    __shared__ unsigned long long cand[AW], fin[AW], nw[AW];
    for (int idx = lane; idx < NNUM * AW; idx += 64)
        ((unsigned long long*)adj_sh)[idx] = g_adj[(size_t)b * NNUM * AW + idx];
    // cand bits + first-argmax (masked and unmasked)
    float bv = -INFINITY; int bi = NNUM;     // masked: where(cand, sc, -inf)
    float bva = -INFINITY; int bia = NNUM;   // unmasked fallback argmax
    for (int k = 0; k < AW; ++k) {
        int j = k * 64 + lane;
        bool cb = false;
        if (j < NNUM) {
            float sc = score[((size_t)b * NNUM + j) * CNUM + c];
            if (sc > bva) { bva = sc; bia = j; }     // strict > keeps first occurrence
            cb = sc > 0.01f;
            if (cb && sc > bv) { bv = sc; bi = j; }
        }
        unsigned long long ball = __ballot(cb);
        if (lane == 0) cand[k] = ball;
    }
    #pragma unroll
    for (int off = 1; off < 64; off <<= 1) {
        float ov = __shfl_xor(bv, off);  int oi = __shfl_xor(bi, off);
        if (ov > bv || (ov == bv && oi < bi)) { bv = ov; bi = oi; }
        float ova = __shfl_xor(bva, off); int oia = __shfl_xor(bia, off);
        if (ova > bva || (ova == bva && oia < bia)) { bva = ova; bia = oia; }
    }
    __syncthreads();
    bool has = (cand[0] | cand[1] | cand[2] | cand[3] | cand[4]) != 0ULL;
    if (!has) {  // fallback: single bit at global argmax
        if (lane < AW) g_fin[(size_t)blk * AW + lane] = ((bia >> 6) == lane) ? (1ULL << (bia & 63)) : 0ULL;
        if (lane == 0) g_cnt[blk] = 1;
        return;
    }
    int seed = bi;
    if (lane < AW) fin[lane] = cand[lane] & adj_sh[seed][lane];
    __syncthreads();
    for (int it = 0; it < NNUM + 2; ++it) {
        for (int k = 0; k < AW; ++k) {
            int j = k * 64 + lane;
            bool nb = false;
            if (j < NNUM && ((cand[k] >> lane) & 1ULL)) {
                unsigned long long o = (adj_sh[j][0] & fin[0]) | (adj_sh[j][1] & fin[1]) |
                                       (adj_sh[j][2] & fin[2]) | (adj_sh[j][3] & fin[3]) |
                                       (adj_sh[j][4] & fin[4]);
                nb = (o != 0ULL);        // adj symmetric: row j == column j
            }
            unsigned long long ball = __ballot(nb);
            if (lane == 0) nw[k] = ball;
        }
        __syncthreads();
        bool ch = (lane < AW) && (nw[lane] != fin[lane]);
        unsigned long long chb = __ballot(ch);
        if (lane < AW) fin[lane] = nw[lane];
        __syncthreads();
        if (chb == 0) break;
    }
    if (lane < AW) g_fin[(size_t)blk * AW + lane] = fin[lane];
    if (lane == 0) {
        int cs = 0;
        for (int w = 0; w < AW; ++w) cs += __popcll(fin[w]);
        g_cnt[blk] = cs;
    }
}

// One block per active (b,c): mean of selected normalized maps.
__global__ void k_meanmap(const int* __restrict__ label) {
    int blk = blockIdx.x;
    if (label[blk] == 0) return;
    int b = blk / CNUM;
    int tid = threadIdx.x;               // 256
    __shared__ unsigned long long f[AW];
    __shared__ float cf;
    if (tid < AW)  f[tid] = g_fin[(size_t)blk * AW + tid];
    if (tid == AW) cf = (float)g_cnt[blk];
    __syncthreads();
    float a0 = 0.f, a1 = 0.f, a2 = 0.f, a3 = 0.f;
    for (int w = 0; w < AW; ++w) {
        unsigned long long word = f[w];
        while (word) {
            int j = w * 64 + (__ffsll((unsigned long long)word) - 1);
            word &= word - 1;
            const float* r = &g_rm[((size_t)b * NNUM + j) * HW];
            a0 += r[tid];
            a1 += r[256 + tid];
            a2 += r[512 + tid];              // 512+255=767 < 784, always valid
            if (tid < 16) a3 += r[768 + tid];
        }
    }
    float cc = cf;
    g_mm[(size_t)blk * HW + tid]       = __fdiv_rn(a0, cc);
    g_mm[(size_t)blk * HW + 256 + tid] = __fdiv_rn(a1, cc);
    g_mm[(size_t)blk * HW + 512 + tid] = __fdiv_rn(a2, cc);
    if (tid < 16) g_mm[(size_t)blk * HW + 768 + tid] = __fdiv_rn(a3, cc);
}

// Fused bilinear upsample (28->448, half-pixel, edge clamp) + BCE partial sums.
__global__ void k_bce(const int* __restrict__ gt, const int* __restrict__ label) {
    int blk = blockIdx.x;
    int bc = blk / TILES, tile = blk - bc * TILES;
    if (label[bc] == 0) return;
    int b = bc / CNUM, c = bc - b * CNUM;
    int tid = threadIdx.x;               // 256
    __shared__ float m[HW];
    for (int p = tid; p < HW; p += 256) m[p] = g_mm[(size_t)bc * HW + p];
    __syncthreads();
    int row0 = tile * TR;
    double part = 0.0;
    for (int idx = tid; idx < TR * GH; idx += 256) {
        int r = idx / GH;
        int oy = row0 + r, ox = idx - r * GH;
        float iy = __fmul_rn((float)oy + 0.5f, 0.0625f) - 0.5f;  // exact multiples of 1/32
        float ix = __fmul_rn((float)ox + 0.5f, 0.0625f) - 0.5f;
        int y0 = (int)floorf(iy); float wy = iy - (float)y0;
        if (y0 < 0) { y0 = 0; wy = 0.0f; } else if (y0 > 26) { y0 = 26; wy = 1.0f; }
        int x0 = (int)floorf(ix); float wx = ix - (float)x0;
        if (x0 < 0) { x0 = 0; wx = 0.0f; } else if (x0 > 26) { x0 = 26; wx = 1.0f; }
        const float* mp = &m[y0 * 28 + x0];
        // rows-first (matches jax's separable resize), no fma contraction
        float av = __fadd_rn(__fmul_rn(mp[0],  1.0f - wy), __fmul_rn(mp[28], wy));
        float bv = __fadd_rn(__fmul_rn(mp[1],  1.0f - wy), __fmul_rn(mp[29], wy));
        float pred = __fadd_rn(__fmul_rn(av, 1.0f - wx), __fmul_rn(bv, wx));
        int g = gt[((size_t)b * GH + oy) * GH + ox];
        bool ypos = (g == c + 1);
        float omp = 1.0f - pred;
        float term = ypos ? ((pred > 0.0f) ? logf(fmaxf(pred, 1e-38f)) : -100.0f)
                          : ((omp  > 0.0f) ? logf(fmaxf(omp,  1e-38f)) : -100.0f);
        part += (double)term;
    }
    __shared__ double red[256];
    red[tid] = part;
    __syncthreads();
    for (int st = 128; st; st >>= 1) {
        if (tid < st) red[tid] += red[tid + st];
        __syncthreads();
    }
    if (tid == 0) atomicAdd(&g_acc, -red[0] * (1.0 / (448.0 * 448.0)));
}

__global__ void k_final(const int* __restrict__ label, float* __restrict__ out) {
    int sa = 0;
    for (int i = 0; i < BNUM * CNUM; ++i) sa += (label[i] != 0) ? 1 : 0;
    out[0] = (float)(g_acc / (double)sa);
}

extern "C" void kernel_launch(void* const* d_in, const int* in_sizes, int n_in,
                              void* d_out, int out_size, void* d_ws, size_t ws_size,
                              hipStream_t stream) {
    const float* sm    = (const float*)d_in[0];   // (L,B,N,784)
    const float* score = (const float*)d_in[1];   // (B,N,C)
    const int*   label = (const int*)d_in[2];     // (B,C)
    const int*   gt    = (const int*)d_in[3];     // (B,448,448)
    float* out = (float*)d_out;

    hipLaunchKernelGGL(k_zero,    dim3(1),                  dim3(1),   0, stream);
    hipLaunchKernelGGL(k_rm,      dim3(BNUM * NNUM),        dim3(256), 0, stream, sm);
    hipLaunchKernelGGL(k_adj,     dim3(BNUM * NNUM),        dim3(320), 0, stream);
    hipLaunchKernelGGL(k_cluster, dim3(BNUM * CNUM),        dim3(64),  0, stream, score, label);
    hipLaunchKernelGGL(k_meanmap, dim3(BNUM * CNUM),        dim3(256), 0, stream, label);
    hipLaunchKernelGGL(k_bce,     dim3(BNUM * CNUM * TILES), dim3(256), 0, stream, gt, label);
    hipLaunchKernelGGL(k_final,   dim3(1),                  dim3(1),   0, stream, label, out);
}

// Round 2
// 62.328 us; speedup vs baseline: 1.7798x; 1.7798x over previous
//
#include <hip/hip_runtime.h>
#include <math.h>

#define LNUM 6
#define BNUM 8
#define NNUM 300
#define CNUM 20
#define HW   784
#define GH   448
#define NW   13   // mask words (784 bits -> 13 x u64)
#define AW   5    // adjacency row words (300 bits -> 5 x u64)
#define RTILE 16  // rows per bce tile
#define NTILE 28  // 448/16 tiles per (b,c)

// ---- device scratch (recomputed every launch; no cross-launch state) ----
__device__ float              g_rm [BNUM*NNUM*HW];
__device__ unsigned long long g_T  [BNUM*NNUM*NW];
__device__ int                g_s  [BNUM*NNUM];
__device__ unsigned long long g_adj[BNUM*NNUM*AW];
__device__ unsigned long long g_fin[BNUM*CNUM*AW];
__device__ int                g_cnt[BNUM*CNUM];
__device__ float              g_mm [BNUM*CNUM*HW];
__device__ double             g_part[BNUM*CNUM*NTILE];   // written by active blocks only; k_final skips inactive

// One block per (b,n): mean over L, relu, max-normalize, write rm + bitmask + popcount.
__global__ void k_rm(const float* __restrict__ sm) {
    int bn  = blockIdx.x;
    int tid = threadIdx.x;               // 256
    __shared__ float wmax[4];
    __shared__ int   scount;
    if (tid == 0) scount = 0;
    const size_t lstride = (size_t)BNUM * NNUM * HW;
    const float* base = sm + (size_t)bn * HW;
    float v[4];
    float lm = 0.0f;
    #pragma unroll
    for (int k = 0; k < 4; ++k) {
        int p = k * 256 + tid;
        float a = 0.0f;
        if (p < HW) {
            #pragma unroll
            for (int l = 0; l < LNUM; ++l) a += base[(size_t)l * lstride + p];
            a = __fdiv_rn(a, 6.0f);      // jnp.mean: sum / L in f32
            a = fmaxf(a, 0.0f);          // relu
        }
        v[k] = a;
        lm = fmaxf(lm, a);
    }
    #pragma unroll
    for (int off = 32; off; off >>= 1) lm = fmaxf(lm, __shfl_xor(lm, off));
    if ((tid & 63) == 0) wmax[tid >> 6] = lm;
    __syncthreads();
    float mx = fmaxf(fmaxf(wmax[0], wmax[1]), fmaxf(wmax[2], wmax[3]));
    float d = mx + 1e-6f;
    #pragma unroll
    for (int k = 0; k < 4; ++k) {
        int p = k * 256 + tid;
        float nv = __fdiv_rn(v[k], d);   // IEEE divide, matches reference rounding
        if (p < HW) g_rm[(size_t)bn * HW + p] = nv;
        bool pr = (p < HW) && (nv > 0.7f);
        unsigned long long ball = __ballot(pr);
        int word = k * 4 + (tid >> 6);
        if ((tid & 63) == 0 && word < NW) {
            g_T[(size_t)bn * NW + word] = ball;
            atomicAdd(&scount, __popcll(ball));
        }
    }
    __syncthreads();
    if (tid == 0) g_s[bn] = scount;
}

// One block per (b,i): adjacency row i via popcount(AND) + exact f32 replication of (iou+dice)/2 > 0.5
__global__ void k_adj() {
    int blk = blockIdx.x;                // b*300 + i
    int b = blk / NNUM;
    int tid = threadIdx.x;               // 320 (5 waves)
    __shared__ unsigned long long Ti[NW];
    __shared__ int si_sh;
    if (tid < NW)  Ti[tid] = g_T[(size_t)blk * NW + tid];
    if (tid == NW) si_sh = g_s[blk];
    __syncthreads();
    bool a = false;
    int j = tid;
    if (j < NNUM) {
        const unsigned long long* Tj = &g_T[((size_t)b * NNUM + j) * NW];
        int inter = 0;
        #pragma unroll
        for (int w = 0; w < NW; ++w) inter += __popcll(Ti[w] & Tj[w]);
        int si = si_sh, sj = g_s[b * NNUM + j];
        int uni = si + sj - inter, tot = si + sj;
        float iou  = (uni == 0) ? 1.0f : __fdiv_rn((float)inter, (float)uni);
        float dice = (tot == 0) ? 1.0f : __fdiv_rn(2.0f * (float)inter, (float)tot);
        a = (0.5f * (iou + dice)) > 0.5f;
    }
    unsigned long long ball = __ballot(a);
    if ((tid & 63) == 0) g_adj[(size_t)blk * AW + (tid >> 6)] = ball;
}

// One wave per (b,c): greedy transitive expansion to fixed point on the bitset graph.
__global__ void k_cluster(const float* __restrict__ score, const int* __restrict__ label) {
    int blk = blockIdx.x;                // b*C + c
    if (label[blk] == 0) return;         // inactive -> never consumed downstream
    int b = blk / CNUM, c = blk - b * CNUM;
    int lane = threadIdx.x;              // 64
    __shared__ unsigned long long adj_sh[NNUM][AW];
    __shared__ unsigned long long cand[AW], fin[AW], nw[AW];
    for (int idx = lane; idx < NNUM * AW; idx += 64)
        ((unsigned long long*)adj_sh)[idx] = g_adj[(size_t)b * NNUM * AW + idx];
    // cand bits + first-argmax (masked and unmasked)
    float bv = -INFINITY; int bi = NNUM;     // masked: where(cand, sc, -inf)
    float bva = -INFINITY; int bia = NNUM;   // unmasked fallback argmax
    for (int k = 0; k < AW; ++k) {
        int j = k * 64 + lane;
        bool cb = false;
        if (j < NNUM) {
            float sc = score[((size_t)b * NNUM + j) * CNUM + c];
            if (sc > bva) { bva = sc; bia = j; }     // strict > keeps first occurrence
            cb = sc > 0.01f;
            if (cb && sc > bv) { bv = sc; bi = j; }
        }
        unsigned long long ball = __ballot(cb);
        if (lane == 0) cand[k] = ball;
    }
    #pragma unroll
    for (int off = 1; off < 64; off <<= 1) {
        float ov = __shfl_xor(bv, off);  int oi = __shfl_xor(bi, off);
        if (ov > bv || (ov == bv && oi < bi)) { bv = ov; bi = oi; }
        float ova = __shfl_xor(bva, off); int oia = __shfl_xor(bia, off);
        if (ova > bva || (ova == bva && oia < bia)) { bva = ova; bia = oia; }
    }
    __syncthreads();
    bool has = (cand[0] | cand[1] | cand[2] | cand[3] | cand[4]) != 0ULL;
    if (!has) {  // fallback: single bit at global argmax
        if (lane < AW) g_fin[(size_t)blk * AW + lane] = ((bia >> 6) == lane) ? (1ULL << (bia & 63)) : 0ULL;
        if (lane == 0) g_cnt[blk] = 1;
        return;
    }
    int seed = bi;
    if (lane < AW) fin[lane] = cand[lane] & adj_sh[seed][lane];
    __syncthreads();
    for (int it = 0; it < NNUM + 2; ++it) {
        for (int k = 0; k < AW; ++k) {
            int j = k * 64 + lane;
            bool nb = false;
            if (j < NNUM && ((cand[k] >> lane) & 1ULL)) {
                unsigned long long o = (adj_sh[j][0] & fin[0]) | (adj_sh[j][1] & fin[1]) |
                                       (adj_sh[j][2] & fin[2]) | (adj_sh[j][3] & fin[3]) |
                                       (adj_sh[j][4] & fin[4]);
                nb = (o != 0ULL);        // adj symmetric: row j == column j
            }
            unsigned long long ball = __ballot(nb);
            if (lane == 0) nw[k] = ball;
        }
        __syncthreads();
        bool ch = (lane < AW) && (nw[lane] != fin[lane]);
        unsigned long long chb = __ballot(ch);
        if (lane < AW) fin[lane] = nw[lane];
        __syncthreads();
        if (chb == 0) break;
    }
    if (lane < AW) g_fin[(size_t)blk * AW + lane] = fin[lane];
    if (lane == 0) {
        int cs = 0;
        for (int w = 0; w < AW; ++w) cs += __popcll(fin[w]);
        g_cnt[blk] = cs;
    }
}

// One block per active (b,c): mean of selected normalized maps.
__global__ void k_meanmap(const int* __restrict__ label) {
    int blk = blockIdx.x;
    if (label[blk] == 0) return;
    int b = blk / CNUM;
    int tid = threadIdx.x;               // 256
    __shared__ unsigned long long f[AW];
    __shared__ float cf;
    if (tid < AW)  f[tid] = g_fin[(size_t)blk * AW + tid];
    if (tid == AW) cf = (float)g_cnt[blk];
    __syncthreads();
    float a0 = 0.f, a1 = 0.f, a2 = 0.f, a3 = 0.f;
    for (int w = 0; w < AW; ++w) {
        unsigned long long word = f[w];
        while (word) {
            int j = w * 64 + (__ffsll((unsigned long long)word) - 1);
            word &= word - 1;
            const float* r = &g_rm[((size_t)b * NNUM + j) * HW];
            a0 += r[tid];
            a1 += r[256 + tid];
            a2 += r[512 + tid];              // 512+255=767 < 784, always valid
            if (tid < 16) a3 += r[768 + tid];
        }
    }
    float cc = cf;
    g_mm[(size_t)blk * HW + tid]       = __fdiv_rn(a0, cc);
    g_mm[(size_t)blk * HW + 256 + tid] = __fdiv_rn(a1, cc);
    g_mm[(size_t)blk * HW + 512 + tid] = __fdiv_rn(a2, cc);
    if (tid < 16) g_mm[(size_t)blk * HW + 768 + tid] = __fdiv_rn(a3, cc);
}

// Fused bilinear upsample (28->448, half-pixel, edge clamp) + BCE partial sums.
// 16-row tile: precompute row-interpolated 16x28 table in LDS, then per pixel:
// 2 LDS reads + 1 fma + gt load + arg-select + one __logf + f64 add.
__global__ void k_bce(const int* __restrict__ gt, const int* __restrict__ label) {
    int blk = blockIdx.x;                // bc*NTILE + tile
    int bc = blk / NTILE, tile = blk - bc * NTILE;
    if (label[bc] == 0) return;          // g_part[blk] never read for inactive bc
    int b = bc / CNUM, c = bc - b * CNUM;
    int tid = threadIdx.x;               // 256
    __shared__ float m[HW];
    __shared__ float rowY[RTILE * 28];
    for (int p = tid; p < HW; p += 256) m[p] = g_mm[(size_t)bc * HW + p];
    __syncthreads();
    int row0 = tile * RTILE;
    for (int idx = tid; idx < RTILE * 28; idx += 256) {
        int r = idx / 28, x = idx - r * 28;
        int oy = row0 + r;
        // iy = (oy+0.5)/16 - 0.5 ; exact multiple of 1/32 -> weights bit-identical to ref
        float iy = fmaf((float)oy, 0.0625f, -0.46875f);
        float y0f = floorf(iy);
        float wy = iy - y0f;
        int y0 = (int)y0f;
        if (y0 < 0) { y0 = 0; wy = 0.0f; } else if (y0 > 26) { y0 = 26; wy = 1.0f; }
        float lo = m[y0 * 28 + x], hi = m[y0 * 28 + 28 + x];
        rowY[idx] = lo + wy * (hi - lo);
    }
    __syncthreads();
    double acc = 0.0;
    int cp1 = c + 1;
    const int* gtb = gt + (size_t)b * GH * GH + (size_t)row0 * GH;
    #pragma unroll
    for (int pass = 0; pass < 2; ++pass) {
        int ox = tid + pass * 256;
        if (ox >= GH) break;             // uniform per thread; sync is after the loop
        float ixc = fmaf((float)ox, 0.0625f, -0.46875f);
        float x0f = floorf(ixc);
        float wx = ixc - x0f;
        int x0 = (int)x0f;
        if (x0 < 0) { x0 = 0; wx = 0.0f; } else if (x0 > 26) { x0 = 26; wx = 1.0f; }
        #pragma unroll 4
        for (int r = 0; r < RTILE; ++r) {
            float rY0 = rowY[r * 28 + x0];
            float rY1 = rowY[r * 28 + x0 + 1];
            float pred = rY0 + wx * (rY1 - rY0);
            int g = gtb[r * GH + ox];
            float xv = (g == cp1) ? pred : 1.0f - pred;
            // pred==0 / 1-pred==0 only via exact zeros (all-nonneg corners), so the
            // -100 branch fires identically to the reference.
            float lg = __logf(fmaxf(xv, 1.175494351e-38f));
            acc += (double)((xv > 0.0f) ? lg : -100.0f);
        }
    }
    #pragma unroll
    for (int off = 32; off; off >>= 1) acc += __shfl_xor(acc, off);
    __shared__ double wsum[4];
    if ((tid & 63) == 0) wsum[tid >> 6] = acc;
    __syncthreads();
    if (tid == 0)
        g_part[blk] = -(wsum[0] + wsum[1] + wsum[2] + wsum[3]) * (1.0 / (448.0 * 448.0));
}

__global__ void k_final(const int* __restrict__ label, float* __restrict__ out) {
    int tid = threadIdx.x;               // 256
    double s = 0.0;
    for (int i = tid; i < BNUM * CNUM * NTILE; i += 256)
        if (label[i / NTILE] != 0) s += g_part[i];
    #pragma unroll
    for (int off = 32; off; off >>= 1) s += __shfl_xor(s, off);
    __shared__ double wsum[4];
    if ((tid & 63) == 0) wsum[tid >> 6] = s;
    __syncthreads();
    if (tid == 0) {
        int sa = 0;
        for (int i = 0; i < BNUM * CNUM; ++i) sa += (label[i] != 0) ? 1 : 0;
        out[0] = (float)((wsum[0] + wsum[1] + wsum[2] + wsum[3]) / (double)sa);
    }
}

extern "C" void kernel_launch(void* const* d_in, const int* in_sizes, int n_in,
                              void* d_out, int out_size, void* d_ws, size_t ws_size,
                              hipStream_t stream) {
    const float* sm    = (const float*)d_in[0];   // (L,B,N,784)
    const float* score = (const float*)d_in[1];   // (B,N,C)
    const int*   label = (const int*)d_in[2];     // (B,C)
    const int*   gt    = (const int*)d_in[3];     // (B,448,448)
    float* out = (float*)d_out;

    hipLaunchKernelGGL(k_rm,      dim3(BNUM * NNUM),          dim3(256), 0, stream, sm);
    hipLaunchKernelGGL(k_adj,     dim3(BNUM * NNUM),          dim3(320), 0, stream);
    hipLaunchKernelGGL(k_cluster, dim3(BNUM * CNUM),          dim3(64),  0, stream, score, label);
    hipLaunchKernelGGL(k_meanmap, dim3(BNUM * CNUM),          dim3(256), 0, stream, label);
    hipLaunchKernelGGL(k_bce,     dim3(BNUM * CNUM * NTILE),  dim3(256), 0, stream, gt, label);
    hipLaunchKernelGGL(k_final,   dim3(1),                    dim3(256), 0, stream, label, out);
}